// Round 1
// baseline (410.388 us; speedup 1.0000x reference)
//
#include <hip/hip_runtime.h>

#define DIM 512
#define QKD 128
#define BATCH 4
#define SEQ 4096

typedef __attribute__((ext_vector_type(8)))  _Float16 f16x8;
typedef __attribute__((ext_vector_type(4)))  _Float16 f16x4;
typedef __attribute__((ext_vector_type(4)))  float    f32x4;
typedef __attribute__((ext_vector_type(16))) float    f32x16;

// ---------------------------------------------------------------------------
// Prep: w_qk fp32 -> fp16 once (128x512 = 64K elems). 64 blocks x 256 thr x 4.
// ---------------------------------------------------------------------------
__global__ __launch_bounds__(256) void wcvt_kernel(
    const float* __restrict__ w, _Float16* __restrict__ w16)
{
    const int i = (blockIdx.x * 256 + threadIdx.x) * 4;
    const float4 v = *(const float4*)(w + i);
    f16x4 o;
    o[0] = (_Float16)v.x; o[1] = (_Float16)v.y;
    o[2] = (_Float16)v.z; o[3] = (_Float16)v.w;
    *(f16x4*)(w16 + i) = o;
}

// ---------------------------------------------------------------------------
// Kernel A: LayerNorm + Linear(512->128) + SiLU + OffsetScale -> q,k (fp16)
// 32 rows per block, 256 threads (4 waves). Weights pre-converted to fp16.
// Folds 1/sqrt(4096) = 1/64 as 1/8 into BOTH q and k (exact pow2 scaling).
// ---------------------------------------------------------------------------
__global__ __launch_bounds__(256) void ln_qk_kernel(
    const float* __restrict__ x,
    const float* __restrict__ ln_w,
    const float* __restrict__ ln_b,
    const _Float16* __restrict__ w16,
    const float* __restrict__ b_qk,
    const float* __restrict__ gamma,
    const float* __restrict__ beta,
    _Float16* __restrict__ q_h,
    _Float16* __restrict__ k_h)
{
    __shared__ _Float16 As[32][520];   // 520-halfs stride: 16B-aligned rows
    const int tid  = threadIdx.x;
    const int wave = tid >> 6;
    const int lane = tid & 63;
    const int row0 = blockIdx.x * 32;

    // per-lane LN params for d = lane*8 .. +7
    float lw[8], lb[8];
    {
        const float4* w4 = (const float4*)ln_w;
        const float4* b4 = (const float4*)ln_b;
        float4 w0 = w4[lane * 2], w1 = w4[lane * 2 + 1];
        float4 b0 = b4[lane * 2], b1 = b4[lane * 2 + 1];
        lw[0]=w0.x; lw[1]=w0.y; lw[2]=w0.z; lw[3]=w0.w;
        lw[4]=w1.x; lw[5]=w1.y; lw[6]=w1.z; lw[7]=w1.w;
        lb[0]=b0.x; lb[1]=b0.y; lb[2]=b0.z; lb[3]=b0.w;
        lb[4]=b1.x; lb[5]=b1.y; lb[6]=b1.z; lb[7]=b1.w;
    }

    // LayerNorm: each wave handles 8 rows
    for (int rr = 0; rr < 8; ++rr) {
        const int r = wave * 8 + rr;
        const float4* xr = (const float4*)(x + (size_t)(row0 + r) * DIM);
        float4 v0 = xr[lane * 2], v1 = xr[lane * 2 + 1];
        float xv[8] = {v0.x, v0.y, v0.z, v0.w, v1.x, v1.y, v1.z, v1.w};
        float s = 0.f, s2 = 0.f;
#pragma unroll
        for (int j = 0; j < 8; ++j) { s += xv[j]; s2 = fmaf(xv[j], xv[j], s2); }
#pragma unroll
        for (int off = 32; off > 0; off >>= 1) {
            s  += __shfl_xor(s,  off);
            s2 += __shfl_xor(s2, off);
        }
        const float mu   = s * (1.f / DIM);
        const float var  = s2 * (1.f / DIM) - mu * mu;
        const float rstd = rsqrtf(var + 1e-5f);
        f16x8 hh;
#pragma unroll
        for (int j = 0; j < 8; ++j)
            hh[j] = (_Float16)(fmaf((xv[j] - mu) * rstd, lw[j], lb[j]));
        *(f16x8*)&As[r][lane * 8] = hh;
    }
    __syncthreads();

    // GEMM: M=32 (2 m-tiles of 16), N=128 (2 n-halves of 64), 16x16x32 MFMA.
    const int mtile = wave & 1;
    const int nbase = (wave >> 1) * 64;
    const int lcol  = lane & 15;
    const int quad  = lane >> 4;

    f32x4 acc[4];
#pragma unroll
    for (int nt = 0; nt < 4; ++nt) acc[nt] = (f32x4){0.f, 0.f, 0.f, 0.f};

    const _Float16* arow = &As[mtile * 16 + lcol][quad * 8];
#pragma unroll 4
    for (int kc = 0; kc < 16; ++kc) {
        const f16x8 af = *(const f16x8*)(arow + kc * 32);
#pragma unroll
        for (int nt = 0; nt < 4; ++nt) {
            const int e = nbase + nt * 16 + lcol;
            const f16x8 bfr = *(const f16x8*)(w16 + (size_t)e * DIM + kc * 32 + quad * 8);
            acc[nt] = __builtin_amdgcn_mfma_f32_16x16x32_f16(af, bfr, acc[nt], 0, 0, 0);
        }
    }

    // epilogue: bias + SiLU + offset-scale (scaled by 1/8), store fp16
#pragma unroll
    for (int nt = 0; nt < 4; ++nt) {
        const int e = nbase + nt * 16 + lcol;
        const float bq  = b_qk[e];
        const float g0  = gamma[e]       * 0.125f;
        const float g1  = gamma[QKD + e] * 0.125f;
        const float be0 = beta[e]        * 0.125f;
        const float be1 = beta[QKD + e]  * 0.125f;
#pragma unroll
        for (int reg = 0; reg < 4; ++reg) {
            const int m  = mtile * 16 + quad * 4 + reg;
            const float v   = acc[nt][reg] + bq;
            const float sil = v / (1.f + __expf(-v));
            const size_t off = (size_t)(row0 + m) * QKD + e;
            q_h[off] = (_Float16)fmaf(sil, g0, be0);
            k_h[off] = (_Float16)fmaf(sil, g1, be1);
        }
    }
}

// ---------------------------------------------------------------------------
// Kernel B1: partial row sums of relu(sim)^2 over a 1024-col chunk.
// 2048 blocks = 4 batch x 128 row-tiles x 4 col-chunks; 256 thr (4 waves).
// VGPR <= 128 via __launch_bounds__(256,4) -> 4 waves/SIMD (2x the old fused
// kernel, which was grid-limited to 2). No stores in the hot loop.
// Block swizzle: l&7 fixes (batch, chunk-half) per XCD -> 512 KB k set in L2.
// ---------------------------------------------------------------------------
__global__ __launch_bounds__(256, 4) void rowsum_kernel(
    const _Float16* __restrict__ q_h,
    const _Float16* __restrict__ k_h,
    float* __restrict__ rsum)          // [BATCH][4][SEQ]
{
    const int l     = blockIdx.x;
    const int batch = (l & 7) >> 1;
    const int chunk = ((l & 1) << 1) | ((l >> 3) & 1);
    const int tile  = l >> 4;          // 0..127
    const int r0    = tile * 32;
    const int c0    = chunk * 1024;

    const int wid  = threadIdx.x >> 6;
    const int lane = threadIdx.x & 63;
    const int n    = lane & 31;     // MFMA n / m lane index
    const int h    = lane >> 5;     // k-half selector

    // q fragments: A[m = n][k = h*8 + j], 8 k-chunks of 16 -> 32 VGPRs
    const _Float16* qb = q_h + ((size_t)batch * SEQ + r0) * QKD;
    f16x8 aq[8];
#pragma unroll
    for (int kc = 0; kc < 8; ++kc)
        aq[kc] = *(const f16x8*)(qb + (size_t)n * QKD + kc * 16 + h * 8);

    const _Float16* kb = k_h + (size_t)batch * SEQ * QKD
                             + (size_t)(c0 + wid * 32 + n) * QKD + h * 8;

    __shared__ float partial[4][32];

    float rs[16];
#pragma unroll
    for (int r = 0; r < 16; ++r) rs[r] = 0.f;

#pragma unroll 2
    for (int ct = 0; ct < 8; ++ct) {
        const _Float16* cb = kb + (size_t)(ct * 128) * QKD;
        f16x8 bf[8];
#pragma unroll
        for (int kc = 0; kc < 8; ++kc) bf[kc] = *(const f16x8*)(cb + kc * 16);

        f32x16 acc;
#pragma unroll
        for (int r = 0; r < 16; ++r) acc[r] = 0.f;
        __builtin_amdgcn_s_setprio(1);
#pragma unroll
        for (int kc = 0; kc < 8; ++kc)
            acc = __builtin_amdgcn_mfma_f32_32x32x16_f16(aq[kc], bf[kc], acc, 0, 0, 0);
        __builtin_amdgcn_s_setprio(0);
#pragma unroll
        for (int r = 0; r < 16; ++r) {
            const float t = fmaxf(acc[r], 0.f);
            rs[r] = fmaf(t, t, rs[r]);
        }
    }

    // reduce row sums across the 32 n-lanes, then across the 4 waves
#pragma unroll
    for (int r = 0; r < 16; ++r) {
        float v = rs[r];
        v += __shfl_xor(v, 1);
        v += __shfl_xor(v, 2);
        v += __shfl_xor(v, 4);
        v += __shfl_xor(v, 8);
        v += __shfl_xor(v, 16);
        if (n == 0) partial[wid][(r & 3) + 8 * (r >> 2) + 4 * h] = v;
    }
    __syncthreads();
    if (threadIdx.x < 32) {
        const float t = partial[0][threadIdx.x] + partial[1][threadIdx.x]
                      + partial[2][threadIdx.x] + partial[3][threadIdx.x];
        rsum[((size_t)batch * 4 + chunk) * SEQ + r0 + threadIdx.x] = t;
    }
}

// ---------------------------------------------------------------------------
// Kernel B2: recompute sim (bit-identical MFMA order), normalize with the
// summed partials, nontemporal store. Same decomposition as B1: 2048 blocks,
// 4 waves/SIMD. Store-BW bound (268 MB fp32 out).
// ---------------------------------------------------------------------------
__global__ __launch_bounds__(256, 4) void attn_norm_kernel(
    const _Float16* __restrict__ q_h,
    const _Float16* __restrict__ k_h,
    const float* __restrict__ rsum,
    float* __restrict__ out)
{
    const int l     = blockIdx.x;
    const int batch = (l & 7) >> 1;
    const int chunk = ((l & 1) << 1) | ((l >> 3) & 1);
    const int tile  = l >> 4;
    const int r0    = tile * 32;
    const int c0    = chunk * 1024;

    const int wid  = threadIdx.x >> 6;
    const int lane = threadIdx.x & 63;
    const int n    = lane & 31;
    const int h    = lane >> 5;

    // issue q loads first so they overlap the rsum load + barrier
    const _Float16* qb = q_h + ((size_t)batch * SEQ + r0) * QKD;
    f16x8 aq[8];
#pragma unroll
    for (int kc = 0; kc < 8; ++kc)
        aq[kc] = *(const f16x8*)(qb + (size_t)n * QKD + kc * 16 + h * 8);

    __shared__ float srow_s[32];
    if (threadIdx.x < 32) {
        const size_t base = (size_t)batch * 4 * SEQ + r0 + threadIdx.x;
        const float t = rsum[base] + rsum[base + SEQ]
                      + rsum[base + 2 * SEQ] + rsum[base + 3 * SEQ];
        srow_s[threadIdx.x] = rsqrtf(t + 1e-6f);  // out = (t*srow)^2 = t^2/(sum+1e-6)
    }
    __syncthreads();

    float srow[16];
#pragma unroll
    for (int r = 0; r < 16; ++r)
        srow[r] = srow_s[(r & 3) + 8 * (r >> 2) + 4 * h];

    const _Float16* kb = k_h + (size_t)batch * SEQ * QKD
                             + (size_t)(c0 + wid * 32 + n) * QKD + h * 8;
    float* ob = out + ((size_t)batch * SEQ + r0) * SEQ;

#pragma unroll 2
    for (int ct = 0; ct < 8; ++ct) {
        const _Float16* cb = kb + (size_t)(ct * 128) * QKD;
        f16x8 bf[8];
#pragma unroll
        for (int kc = 0; kc < 8; ++kc) bf[kc] = *(const f16x8*)(cb + kc * 16);

        f32x16 acc;
#pragma unroll
        for (int r = 0; r < 16; ++r) acc[r] = 0.f;
        __builtin_amdgcn_s_setprio(1);
#pragma unroll
        for (int kc = 0; kc < 8; ++kc)
            acc = __builtin_amdgcn_mfma_f32_32x32x16_f16(aq[kc], bf[kc], acc, 0, 0, 0);
        __builtin_amdgcn_s_setprio(0);

        const int col = c0 + ct * 128 + wid * 32 + n;
#pragma unroll
        for (int r = 0; r < 16; ++r) {
            const float t   = fmaxf(acc[r], 0.f) * srow[r];
            const int   row = (r & 3) + 8 * (r >> 2) + 4 * h;
            __builtin_nontemporal_store(t * t, ob + (size_t)row * SEQ + col);
        }
    }
}

extern "C" void kernel_launch(void* const* d_in, const int* in_sizes, int n_in,
                              void* d_out, int out_size, void* d_ws, size_t ws_size,
                              hipStream_t stream) {
    const float* x     = (const float*)d_in[0];
    const float* ln_w  = (const float*)d_in[1];
    const float* ln_b  = (const float*)d_in[2];
    const float* w_qk  = (const float*)d_in[3];
    const float* b_qk  = (const float*)d_in[4];
    const float* gamma = (const float*)d_in[5];
    const float* beta  = (const float*)d_in[6];
    float* out = (float*)d_out;

    _Float16* q_h = (_Float16*)d_ws;                            // 4 MB
    _Float16* k_h = q_h + (size_t)BATCH * SEQ * QKD;            // 4 MB
    _Float16* w16 = k_h + (size_t)BATCH * SEQ * QKD;            // 128 KB
    float*    rsum = (float*)(w16 + (size_t)QKD * DIM);         // 256 KB

    hipLaunchKernelGGL(wcvt_kernel, dim3(64), dim3(256), 0, stream, w_qk, w16);
    hipLaunchKernelGGL(ln_qk_kernel, dim3((BATCH * SEQ) / 32), dim3(256), 0, stream,
                       x, ln_w, ln_b, w16, b_qk, gamma, beta, q_h, k_h);
    hipLaunchKernelGGL(rowsum_kernel, dim3(2048), dim3(256), 0, stream,
                       q_h, k_h, rsum);
    hipLaunchKernelGGL(attn_norm_kernel, dim3(2048), dim3(256), 0, stream,
                       q_h, k_h, rsum, out);
}

// Round 2
// 346.778 us; speedup vs baseline: 1.1834x; 1.1834x over previous
//
#include <hip/hip_runtime.h>

#define DIM 512
#define QKD 128
#define BATCH 4
#define SEQ 4096

typedef __attribute__((ext_vector_type(8)))  _Float16 f16x8;
typedef __attribute__((ext_vector_type(4)))  _Float16 f16x4;
typedef __attribute__((ext_vector_type(4)))  float    f32x4;
typedef __attribute__((ext_vector_type(16))) float    f32x16;

// ---------------------------------------------------------------------------
// Prep: w_qk fp32 -> fp16 once (128x512 = 64K elems). 64 blocks x 256 thr x 4.
// ---------------------------------------------------------------------------
__global__ __launch_bounds__(256) void wcvt_kernel(
    const float* __restrict__ w, _Float16* __restrict__ w16)
{
    const int i = (blockIdx.x * 256 + threadIdx.x) * 4;
    const float4 v = *(const float4*)(w + i);
    f16x4 o;
    o[0] = (_Float16)v.x; o[1] = (_Float16)v.y;
    o[2] = (_Float16)v.z; o[3] = (_Float16)v.w;
    *(f16x4*)(w16 + i) = o;
}

// ---------------------------------------------------------------------------
// Kernel A: LayerNorm + Linear(512->128) + SiLU + OffsetScale -> q,k (fp16)
// 32 rows per block, 256 threads (4 waves). Weights pre-converted to fp16.
// Folds 1/sqrt(4096) = 1/64 as 1/8 into BOTH q and k (exact pow2 scaling).
//
// R2: q/k are stored in MFMA-FRAGMENT ORDER instead of [row][d]:
//   layout [row_block g=row/32][kc=d>>4][lane=((d>>3)&1)*32 + row%32][j=d&7]
// so the attention kernels' fragment loads are contiguous 1 KB per wave
// instruction (was: 64x16B at 256-B stride = 32 cache lines per instr, which
// serialized in L1 and starved the MFMA pipe). Value->lane mapping is
// unchanged -> bit-identical MFMA inputs.
// ---------------------------------------------------------------------------
__global__ __launch_bounds__(256) void ln_qk_kernel(
    const float* __restrict__ x,
    const float* __restrict__ ln_w,
    const float* __restrict__ ln_b,
    const _Float16* __restrict__ w16,
    const float* __restrict__ b_qk,
    const float* __restrict__ gamma,
    const float* __restrict__ beta,
    _Float16* __restrict__ q_h,
    _Float16* __restrict__ k_h)
{
    __shared__ _Float16 As[32][520];   // 520-halfs stride: 16B-aligned rows
    const int tid  = threadIdx.x;
    const int wave = tid >> 6;
    const int lane = tid & 63;
    const int row0 = blockIdx.x * 32;

    // per-lane LN params for d = lane*8 .. +7
    float lw[8], lb[8];
    {
        const float4* w4 = (const float4*)ln_w;
        const float4* b4 = (const float4*)ln_b;
        float4 w0 = w4[lane * 2], w1 = w4[lane * 2 + 1];
        float4 b0 = b4[lane * 2], b1 = b4[lane * 2 + 1];
        lw[0]=w0.x; lw[1]=w0.y; lw[2]=w0.z; lw[3]=w0.w;
        lw[4]=w1.x; lw[5]=w1.y; lw[6]=w1.z; lw[7]=w1.w;
        lb[0]=b0.x; lb[1]=b0.y; lb[2]=b0.z; lb[3]=b0.w;
        lb[4]=b1.x; lb[5]=b1.y; lb[6]=b1.z; lb[7]=b1.w;
    }

    // LayerNorm: each wave handles 8 rows
    for (int rr = 0; rr < 8; ++rr) {
        const int r = wave * 8 + rr;
        const float4* xr = (const float4*)(x + (size_t)(row0 + r) * DIM);
        float4 v0 = xr[lane * 2], v1 = xr[lane * 2 + 1];
        float xv[8] = {v0.x, v0.y, v0.z, v0.w, v1.x, v1.y, v1.z, v1.w};
        float s = 0.f, s2 = 0.f;
#pragma unroll
        for (int j = 0; j < 8; ++j) { s += xv[j]; s2 = fmaf(xv[j], xv[j], s2); }
#pragma unroll
        for (int off = 32; off > 0; off >>= 1) {
            s  += __shfl_xor(s,  off);
            s2 += __shfl_xor(s2, off);
        }
        const float mu   = s * (1.f / DIM);
        const float var  = s2 * (1.f / DIM) - mu * mu;
        const float rstd = rsqrtf(var + 1e-5f);
        f16x8 hh;
#pragma unroll
        for (int j = 0; j < 8; ++j)
            hh[j] = (_Float16)(fmaf((xv[j] - mu) * rstd, lw[j], lb[j]));
        *(f16x8*)&As[r][lane * 8] = hh;
    }
    __syncthreads();

    // GEMM: M=32 (2 m-tiles of 16), N=128 (2 n-halves of 64), 16x16x32 MFMA.
    const int mtile = wave & 1;
    const int nbase = (wave >> 1) * 64;
    const int lcol  = lane & 15;
    const int quad  = lane >> 4;

    f32x4 acc[4];
#pragma unroll
    for (int nt = 0; nt < 4; ++nt) acc[nt] = (f32x4){0.f, 0.f, 0.f, 0.f};

    const _Float16* arow = &As[mtile * 16 + lcol][quad * 8];
#pragma unroll 4
    for (int kc = 0; kc < 16; ++kc) {
        const f16x8 af = *(const f16x8*)(arow + kc * 32);
#pragma unroll
        for (int nt = 0; nt < 4; ++nt) {
            const int e = nbase + nt * 16 + lcol;
            const f16x8 bfr = *(const f16x8*)(w16 + (size_t)e * DIM + kc * 32 + quad * 8);
            acc[nt] = __builtin_amdgcn_mfma_f32_16x16x32_f16(af, bfr, acc[nt], 0, 0, 0);
        }
    }

    // epilogue: bias + SiLU + offset-scale (scaled by 1/8), store fp16 in
    // fragment order: off = g*4096 + (e>>3)*256 + m*8 + (e&7)
    const size_t gbase = (size_t)blockIdx.x * 4096;
#pragma unroll
    for (int nt = 0; nt < 4; ++nt) {
        const int e = nbase + nt * 16 + lcol;
        const float bq  = b_qk[e];
        const float g0  = gamma[e]       * 0.125f;
        const float g1  = gamma[QKD + e] * 0.125f;
        const float be0 = beta[e]        * 0.125f;
        const float be1 = beta[QKD + e]  * 0.125f;
        const int eo = (e >> 3) * 256 + (e & 7);
#pragma unroll
        for (int reg = 0; reg < 4; ++reg) {
            const int m  = mtile * 16 + quad * 4 + reg;
            const float v   = acc[nt][reg] + bq;
            const float sil = v / (1.f + __expf(-v));
            const size_t off = gbase + (size_t)(eo + m * 8);
            q_h[off] = (_Float16)fmaf(sil, g0, be0);
            k_h[off] = (_Float16)fmaf(sil, g1, be1);
        }
    }
}

// ---------------------------------------------------------------------------
// Kernel B1: partial row sums of relu(sim)^2 over a 1024-col chunk.
// 2048 blocks = 4 batch x 128 row-tiles x 4 col-chunks; 256 thr (4 waves).
// Fragment-order q/k: every load is 64 lanes x 16 B CONTIGUOUS (1 KB/instr,
// 8 lines fully consumed) -> streaming from L2, no L1 serialization.
// ---------------------------------------------------------------------------
__global__ __launch_bounds__(256, 4) void rowsum_kernel(
    const _Float16* __restrict__ q_h,
    const _Float16* __restrict__ k_h,
    float* __restrict__ rsum)          // [BATCH][4][SEQ]
{
    const int l     = blockIdx.x;
    const int batch = (l & 7) >> 1;
    const int chunk = ((l & 1) << 1) | ((l >> 3) & 1);
    const int tile  = l >> 4;          // 0..127
    const int r0    = tile * 32;

    const int wid  = threadIdx.x >> 6;
    const int lane = threadIdx.x & 63;
    const int n    = lane & 31;     // MFMA n / m lane index
    const int h    = lane >> 5;     // k-half selector

    // q fragments: contiguous 4 KB block per row-tile
    const _Float16* qb = q_h + (size_t)(batch * 128 + tile) * 4096;
    f16x8 aq[8];
#pragma unroll
    for (int kc = 0; kc < 8; ++kc)
        aq[kc] = *(const f16x8*)(qb + kc * 512 + lane * 8);

    // k fragment base for this wave's first col-block
    const _Float16* kb0 = k_h + (size_t)(batch * 128 + chunk * 32 + wid) * 4096
                              + lane * 8;

    __shared__ float partial[4][32];

    float rs[16];
#pragma unroll
    for (int r = 0; r < 16; ++r) rs[r] = 0.f;

#pragma unroll 2
    for (int ct = 0; ct < 8; ++ct) {
        const _Float16* cb = kb0 + (size_t)(ct * 4) * 4096;
        f16x8 bf[8];
#pragma unroll
        for (int kc = 0; kc < 8; ++kc) bf[kc] = *(const f16x8*)(cb + kc * 512);

        f32x16 acc;
#pragma unroll
        for (int r = 0; r < 16; ++r) acc[r] = 0.f;
        __builtin_amdgcn_s_setprio(1);
#pragma unroll
        for (int kc = 0; kc < 8; ++kc)
            acc = __builtin_amdgcn_mfma_f32_32x32x16_f16(aq[kc], bf[kc], acc, 0, 0, 0);
        __builtin_amdgcn_s_setprio(0);
#pragma unroll
        for (int r = 0; r < 16; ++r) {
            const float t = fmaxf(acc[r], 0.f);
            rs[r] = fmaf(t, t, rs[r]);
        }
    }

    // reduce row sums across the 32 n-lanes, then across the 4 waves
#pragma unroll
    for (int r = 0; r < 16; ++r) {
        float v = rs[r];
        v += __shfl_xor(v, 1);
        v += __shfl_xor(v, 2);
        v += __shfl_xor(v, 4);
        v += __shfl_xor(v, 8);
        v += __shfl_xor(v, 16);
        if (n == 0) partial[wid][(r & 3) + 8 * (r >> 2) + 4 * h] = v;
    }
    __syncthreads();
    if (threadIdx.x < 32) {
        const float t = partial[0][threadIdx.x] + partial[1][threadIdx.x]
                      + partial[2][threadIdx.x] + partial[3][threadIdx.x];
        rsum[((size_t)batch * 4 + chunk) * SEQ + r0 + threadIdx.x] = t;
    }
}

// ---------------------------------------------------------------------------
// Kernel B2: recompute sim (bit-identical MFMA order), normalize with the
// summed partials, nontemporal store. Same decomposition as B1.
// Store-BW bound (268 MB fp32 out).
// ---------------------------------------------------------------------------
__global__ __launch_bounds__(256, 4) void attn_norm_kernel(
    const _Float16* __restrict__ q_h,
    const _Float16* __restrict__ k_h,
    const float* __restrict__ rsum,
    float* __restrict__ out)
{
    const int l     = blockIdx.x;
    const int batch = (l & 7) >> 1;
    const int chunk = ((l & 1) << 1) | ((l >> 3) & 1);
    const int tile  = l >> 4;
    const int r0    = tile * 32;
    const int c0    = chunk * 1024;

    const int wid  = threadIdx.x >> 6;
    const int lane = threadIdx.x & 63;
    const int n    = lane & 31;
    const int h    = lane >> 5;

    // issue q loads first so they overlap the rsum load + barrier
    const _Float16* qb = q_h + (size_t)(batch * 128 + tile) * 4096;
    f16x8 aq[8];
#pragma unroll
    for (int kc = 0; kc < 8; ++kc)
        aq[kc] = *(const f16x8*)(qb + kc * 512 + lane * 8);

    __shared__ float srow_s[32];
    if (threadIdx.x < 32) {
        const size_t base = (size_t)batch * 4 * SEQ + r0 + threadIdx.x;
        const float t = rsum[base] + rsum[base + SEQ]
                      + rsum[base + 2 * SEQ] + rsum[base + 3 * SEQ];
        srow_s[threadIdx.x] = rsqrtf(t + 1e-6f);  // out = (t*srow)^2 = t^2/(sum+1e-6)
    }
    __syncthreads();

    float srow[16];
#pragma unroll
    for (int r = 0; r < 16; ++r)
        srow[r] = srow_s[(r & 3) + 8 * (r >> 2) + 4 * h];

    const _Float16* kb0 = k_h + (size_t)(batch * 128 + chunk * 32 + wid) * 4096
                              + lane * 8;
    float* ob = out + ((size_t)batch * SEQ + r0) * SEQ;

#pragma unroll 2
    for (int ct = 0; ct < 8; ++ct) {
        const _Float16* cb = kb0 + (size_t)(ct * 4) * 4096;
        f16x8 bf[8];
#pragma unroll
        for (int kc = 0; kc < 8; ++kc) bf[kc] = *(const f16x8*)(cb + kc * 512);

        f32x16 acc;
#pragma unroll
        for (int r = 0; r < 16; ++r) acc[r] = 0.f;
        __builtin_amdgcn_s_setprio(1);
#pragma unroll
        for (int kc = 0; kc < 8; ++kc)
            acc = __builtin_amdgcn_mfma_f32_32x32x16_f16(aq[kc], bf[kc], acc, 0, 0, 0);
        __builtin_amdgcn_s_setprio(0);

        const int col = c0 + ct * 128 + wid * 32 + n;
#pragma unroll
        for (int r = 0; r < 16; ++r) {
            const float t   = fmaxf(acc[r], 0.f) * srow[r];
            const int   row = (r & 3) + 8 * (r >> 2) + 4 * h;
            __builtin_nontemporal_store(t * t, ob + (size_t)row * SEQ + col);
        }
    }
}

extern "C" void kernel_launch(void* const* d_in, const int* in_sizes, int n_in,
                              void* d_out, int out_size, void* d_ws, size_t ws_size,
                              hipStream_t stream) {
    const float* x     = (const float*)d_in[0];
    const float* ln_w  = (const float*)d_in[1];
    const float* ln_b  = (const float*)d_in[2];
    const float* w_qk  = (const float*)d_in[3];
    const float* b_qk  = (const float*)d_in[4];
    const float* gamma = (const float*)d_in[5];
    const float* beta  = (const float*)d_in[6];
    float* out = (float*)d_out;

    _Float16* q_h = (_Float16*)d_ws;                            // 4 MB
    _Float16* k_h = q_h + (size_t)BATCH * SEQ * QKD;            // 4 MB
    _Float16* w16 = k_h + (size_t)BATCH * SEQ * QKD;            // 128 KB
    float*    rsum = (float*)(w16 + (size_t)QKD * DIM);         // 256 KB

    hipLaunchKernelGGL(wcvt_kernel, dim3(64), dim3(256), 0, stream, w_qk, w16);
    hipLaunchKernelGGL(ln_qk_kernel, dim3((BATCH * SEQ) / 32), dim3(256), 0, stream,
                       x, ln_w, ln_b, w16, b_qk, gamma, beta, q_h, k_h);
    hipLaunchKernelGGL(rowsum_kernel, dim3(2048), dim3(256), 0, stream,
                       q_h, k_h, rsum);
    hipLaunchKernelGGL(attn_norm_kernel, dim3(2048), dim3(256), 0, stream,
                       q_h, k_h, rsum, out);
}

// Round 3
// 342.015 us; speedup vs baseline: 1.1999x; 1.0139x over previous
//
#include <hip/hip_runtime.h>

#define DIM 512
#define QKD 128
#define BATCH 4
#define SEQ 4096

typedef __attribute__((ext_vector_type(8)))  _Float16 f16x8;
typedef __attribute__((ext_vector_type(4)))  _Float16 f16x4;
typedef __attribute__((ext_vector_type(4)))  float    f32x4;
typedef __attribute__((ext_vector_type(16))) float    f32x16;

// ---------------------------------------------------------------------------
// Prep: w_qk fp32 -> fp16, permuted to MFMA-fragment order for kernel A:
//   w16f[kc][nb][lane][j] = w[e = nb*16 + (lane&15)][d = kc*32 + (lane>>4)*8 + j]
// so A's B-operand loads are contiguous 1 KB per wave instruction.
// 8192 threads, one f16x8 each. 32 blocks x 256.
// ---------------------------------------------------------------------------
__global__ __launch_bounds__(256) void wcvt_kernel(
    const float* __restrict__ w, _Float16* __restrict__ w16f)
{
    const int t    = blockIdx.x * 256 + threadIdx.x;   // 0..8191
    const int lane = t & 63;
    const int nb   = (t >> 6) & 7;
    const int kc   = t >> 9;                           // 0..15
    const int e    = nb * 16 + (lane & 15);
    const int d0   = kc * 32 + (lane >> 4) * 8;
    const float4* src = (const float4*)(w + (size_t)e * DIM + d0);
    const float4 a = src[0], b = src[1];
    f16x8 o;
    o[0] = (_Float16)a.x; o[1] = (_Float16)a.y;
    o[2] = (_Float16)a.z; o[3] = (_Float16)a.w;
    o[4] = (_Float16)b.x; o[5] = (_Float16)b.y;
    o[6] = (_Float16)b.z; o[7] = (_Float16)b.w;
    *(f16x8*)(w16f + (size_t)t * 8) = o;
}

// ---------------------------------------------------------------------------
// Kernel A: LayerNorm + Linear(512->128) + SiLU + OffsetScale -> q,k (fp16)
// 32 rows per block, 256 threads (4 waves). Folds 1/sqrt(4096) as 1/8 into
// both q and k. Outputs in MFMA-fragment order (see R2 note):
//   off = g*4096 + (e>>3)*256 + m*8 + (e&7),  g = row/32, m = row%32
// R3: B-operand loads now contiguous via w16f fragment order.
// ---------------------------------------------------------------------------
__global__ __launch_bounds__(256) void ln_qk_kernel(
    const float* __restrict__ x,
    const float* __restrict__ ln_w,
    const float* __restrict__ ln_b,
    const _Float16* __restrict__ w16f,
    const float* __restrict__ b_qk,
    const float* __restrict__ gamma,
    const float* __restrict__ beta,
    _Float16* __restrict__ q_h,
    _Float16* __restrict__ k_h)
{
    __shared__ _Float16 As[32][520];   // 520-halfs stride: 16B-aligned rows
    const int tid  = threadIdx.x;
    const int wave = tid >> 6;
    const int lane = tid & 63;
    const int row0 = blockIdx.x * 32;

    // per-lane LN params for d = lane*8 .. +7
    float lw[8], lb[8];
    {
        const float4* w4 = (const float4*)ln_w;
        const float4* b4 = (const float4*)ln_b;
        float4 w0 = w4[lane * 2], w1 = w4[lane * 2 + 1];
        float4 b0 = b4[lane * 2], b1 = b4[lane * 2 + 1];
        lw[0]=w0.x; lw[1]=w0.y; lw[2]=w0.z; lw[3]=w0.w;
        lw[4]=w1.x; lw[5]=w1.y; lw[6]=w1.z; lw[7]=w1.w;
        lb[0]=b0.x; lb[1]=b0.y; lb[2]=b0.z; lb[3]=b0.w;
        lb[4]=b1.x; lb[5]=b1.y; lb[6]=b1.z; lb[7]=b1.w;
    }

    // LayerNorm: each wave handles 8 rows
    for (int rr = 0; rr < 8; ++rr) {
        const int r = wave * 8 + rr;
        const float4* xr = (const float4*)(x + (size_t)(row0 + r) * DIM);
        float4 v0 = xr[lane * 2], v1 = xr[lane * 2 + 1];
        float xv[8] = {v0.x, v0.y, v0.z, v0.w, v1.x, v1.y, v1.z, v1.w};
        float s = 0.f, s2 = 0.f;
#pragma unroll
        for (int j = 0; j < 8; ++j) { s += xv[j]; s2 = fmaf(xv[j], xv[j], s2); }
#pragma unroll
        for (int off = 32; off > 0; off >>= 1) {
            s  += __shfl_xor(s,  off);
            s2 += __shfl_xor(s2, off);
        }
        const float mu   = s * (1.f / DIM);
        const float var  = s2 * (1.f / DIM) - mu * mu;
        const float rstd = rsqrtf(var + 1e-5f);
        f16x8 hh;
#pragma unroll
        for (int j = 0; j < 8; ++j)
            hh[j] = (_Float16)(fmaf((xv[j] - mu) * rstd, lw[j], lb[j]));
        *(f16x8*)&As[r][lane * 8] = hh;
    }
    __syncthreads();

    // GEMM: M=32 (2 m-tiles of 16), N=128 (8 n-blocks of 16), 16x16x32 MFMA.
    const int mtile = wave & 1;
    const int nb0   = (wave >> 1) * 4;   // first n-block of this wave
    const int lcol  = lane & 15;
    const int quad  = lane >> 4;

    f32x4 acc[4];
#pragma unroll
    for (int nt = 0; nt < 4; ++nt) acc[nt] = (f32x4){0.f, 0.f, 0.f, 0.f};

    const _Float16* arow = &As[mtile * 16 + lcol][quad * 8];
#pragma unroll 4
    for (int kc = 0; kc < 16; ++kc) {
        const f16x8 af = *(const f16x8*)(arow + kc * 32);
#pragma unroll
        for (int nt = 0; nt < 4; ++nt) {
            const f16x8 bfr = *(const f16x8*)(
                w16f + (size_t)((kc * 8 + nb0 + nt) * 64 + lane) * 8);
            acc[nt] = __builtin_amdgcn_mfma_f32_16x16x32_f16(af, bfr, acc[nt], 0, 0, 0);
        }
    }

    // epilogue: bias + SiLU + offset-scale (scaled by 1/8), store fp16 in
    // fragment order: off = g*4096 + (e>>3)*256 + m*8 + (e&7)
    const size_t gbase = (size_t)blockIdx.x * 4096;
#pragma unroll
    for (int nt = 0; nt < 4; ++nt) {
        const int e = (nb0 + nt) * 16 + lcol;
        const float bq  = b_qk[e];
        const float g0  = gamma[e]       * 0.125f;
        const float g1  = gamma[QKD + e] * 0.125f;
        const float be0 = beta[e]        * 0.125f;
        const float be1 = beta[QKD + e]  * 0.125f;
        const int eo = (e >> 3) * 256 + (e & 7);
#pragma unroll
        for (int reg = 0; reg < 4; ++reg) {
            const int m  = mtile * 16 + quad * 4 + reg;
            const float v   = acc[nt][reg] + bq;
            const float sil = v / (1.f + __expf(-v));
            const size_t off = gbase + (size_t)(eo + m * 8);
            q_h[off] = (_Float16)fmaf(sil, g0, be0);
            k_h[off] = (_Float16)fmaf(sil, g1, be1);
        }
    }
}

// ---------------------------------------------------------------------------
// Kernel B1: partial row sums of relu(sim)^2 over a 1024-col chunk.
// R3: 64-row tiles, 512 threads (8 waves = 2 row-blocks x 4 col-waves).
// The two row-block waves sharing a col-wave read IDENTICAL k blocks -> L1
// hits halve L2 k traffic (512 -> 256 MB). 1024 blocks; 4 waves/SIMD.
// ---------------------------------------------------------------------------
__global__ __launch_bounds__(512, 4) void rowsum_kernel(
    const _Float16* __restrict__ q_h,
    const _Float16* __restrict__ k_h,
    float* __restrict__ rsum)          // [BATCH][4][SEQ]
{
    const int l     = blockIdx.x;
    const int batch = (l & 7) >> 1;
    const int chunk = ((l & 1) << 1) | ((l >> 3) & 1);
    const int tile  = l >> 4;          // 0..63 (64-row tiles)

    const int wid    = threadIdx.x >> 6;
    const int rowblk = wid >> 2;       // 0..1
    const int colw   = wid & 3;        // 0..3
    const int lane   = threadIdx.x & 63;
    const int n      = lane & 31;
    const int h      = lane >> 5;

    // q fragments: contiguous 4 KB block per 32-row group
    const _Float16* qb = q_h + (size_t)(batch * 128 + tile * 2 + rowblk) * 4096;
    f16x8 aq[8];
#pragma unroll
    for (int kc = 0; kc < 8; ++kc)
        aq[kc] = *(const f16x8*)(qb + kc * 512 + lane * 8);

    // k fragment base: col-block index = chunk*32 + ct*4 + colw
    const _Float16* kb0 = k_h + (size_t)(batch * 128 + chunk * 32 + colw) * 4096
                              + lane * 8;

    __shared__ float partial[8][32];

    float rs[16];
#pragma unroll
    for (int r = 0; r < 16; ++r) rs[r] = 0.f;

#pragma unroll 2
    for (int ct = 0; ct < 8; ++ct) {
        const _Float16* cb = kb0 + (size_t)(ct * 4) * 4096;
        f16x8 bf[8];
#pragma unroll
        for (int kc = 0; kc < 8; ++kc) bf[kc] = *(const f16x8*)(cb + kc * 512);

        f32x16 acc;
#pragma unroll
        for (int r = 0; r < 16; ++r) acc[r] = 0.f;
        __builtin_amdgcn_s_setprio(1);
#pragma unroll
        for (int kc = 0; kc < 8; ++kc)
            acc = __builtin_amdgcn_mfma_f32_32x32x16_f16(aq[kc], bf[kc], acc, 0, 0, 0);
        __builtin_amdgcn_s_setprio(0);
#pragma unroll
        for (int r = 0; r < 16; ++r) {
            const float t = fmaxf(acc[r], 0.f);
            rs[r] = fmaf(t, t, rs[r]);
        }
    }

    // reduce row sums across the 32 n-lanes, then across the 4 col-waves
#pragma unroll
    for (int r = 0; r < 16; ++r) {
        float v = rs[r];
        v += __shfl_xor(v, 1);
        v += __shfl_xor(v, 2);
        v += __shfl_xor(v, 4);
        v += __shfl_xor(v, 8);
        v += __shfl_xor(v, 16);
        if (n == 0) partial[wid][(r & 3) + 8 * (r >> 2) + 4 * h] = v;
    }
    __syncthreads();
    if (threadIdx.x < 64) {
        const int rb  = threadIdx.x >> 5;
        const int idx = threadIdx.x & 31;
        const float t = partial[rb * 4 + 0][idx] + partial[rb * 4 + 1][idx]
                      + partial[rb * 4 + 2][idx] + partial[rb * 4 + 3][idx];
        rsum[((size_t)batch * 4 + chunk) * SEQ + tile * 64 + rb * 32 + idx] = t;
    }
}

// ---------------------------------------------------------------------------
// Kernel B2: recompute sim (bit-identical MFMA order), normalize with the
// summed partials, nontemporal store. Same 64-row decomposition as B1.
// Store-BW bound (268 MB fp32 out); per-wave store pattern unchanged
// (2 x 128-B fully-coalesced segments per instruction).
// ---------------------------------------------------------------------------
__global__ __launch_bounds__(512, 4) void attn_norm_kernel(
    const _Float16* __restrict__ q_h,
    const _Float16* __restrict__ k_h,
    const float* __restrict__ rsum,
    float* __restrict__ out)
{
    const int l     = blockIdx.x;
    const int batch = (l & 7) >> 1;
    const int chunk = ((l & 1) << 1) | ((l >> 3) & 1);
    const int tile  = l >> 4;          // 0..63
    const int c0    = chunk * 1024;

    const int wid    = threadIdx.x >> 6;
    const int rowblk = wid >> 2;
    const int colw   = wid & 3;
    const int lane   = threadIdx.x & 63;
    const int n      = lane & 31;
    const int h      = lane >> 5;

    // issue q loads first so they overlap the rsum load + barrier
    const _Float16* qb = q_h + (size_t)(batch * 128 + tile * 2 + rowblk) * 4096;
    f16x8 aq[8];
#pragma unroll
    for (int kc = 0; kc < 8; ++kc)
        aq[kc] = *(const f16x8*)(qb + kc * 512 + lane * 8);

    __shared__ float srow_s[64];
    if (threadIdx.x < 64) {
        const size_t base = (size_t)batch * 4 * SEQ + tile * 64 + threadIdx.x;
        const float t = rsum[base] + rsum[base + SEQ]
                      + rsum[base + 2 * SEQ] + rsum[base + 3 * SEQ];
        srow_s[threadIdx.x] = rsqrtf(t + 1e-6f);  // out = (t*srow)^2 = t^2/(sum+1e-6)
    }
    __syncthreads();

    float srow[16];
#pragma unroll
    for (int r = 0; r < 16; ++r)
        srow[r] = srow_s[rowblk * 32 + (r & 3) + 8 * (r >> 2) + 4 * h];

    const _Float16* kb0 = k_h + (size_t)(batch * 128 + chunk * 32 + colw) * 4096
                              + lane * 8;
    float* ob = out + ((size_t)batch * SEQ + tile * 64 + rowblk * 32) * SEQ;

#pragma unroll 2
    for (int ct = 0; ct < 8; ++ct) {
        const _Float16* cb = kb0 + (size_t)(ct * 4) * 4096;
        f16x8 bf[8];
#pragma unroll
        for (int kc = 0; kc < 8; ++kc) bf[kc] = *(const f16x8*)(cb + kc * 512);

        f32x16 acc;
#pragma unroll
        for (int r = 0; r < 16; ++r) acc[r] = 0.f;
        __builtin_amdgcn_s_setprio(1);
#pragma unroll
        for (int kc = 0; kc < 8; ++kc)
            acc = __builtin_amdgcn_mfma_f32_32x32x16_f16(aq[kc], bf[kc], acc, 0, 0, 0);
        __builtin_amdgcn_s_setprio(0);

        const int col = c0 + ct * 128 + colw * 32 + n;
#pragma unroll
        for (int r = 0; r < 16; ++r) {
            const float t   = fmaxf(acc[r], 0.f) * srow[r];
            const int   row = (r & 3) + 8 * (r >> 2) + 4 * h;
            __builtin_nontemporal_store(t * t, ob + (size_t)row * SEQ + col);
        }
    }
}

extern "C" void kernel_launch(void* const* d_in, const int* in_sizes, int n_in,
                              void* d_out, int out_size, void* d_ws, size_t ws_size,
                              hipStream_t stream) {
    const float* x     = (const float*)d_in[0];
    const float* ln_w  = (const float*)d_in[1];
    const float* ln_b  = (const float*)d_in[2];
    const float* w_qk  = (const float*)d_in[3];
    const float* b_qk  = (const float*)d_in[4];
    const float* gamma = (const float*)d_in[5];
    const float* beta  = (const float*)d_in[6];
    float* out = (float*)d_out;

    _Float16* q_h  = (_Float16*)d_ws;                           // 4 MB
    _Float16* k_h  = q_h + (size_t)BATCH * SEQ * QKD;           // 4 MB
    _Float16* w16f = k_h + (size_t)BATCH * SEQ * QKD;           // 128 KB
    float*    rsum = (float*)(w16f + (size_t)QKD * DIM);        // 256 KB

    hipLaunchKernelGGL(wcvt_kernel, dim3(32), dim3(256), 0, stream, w_qk, w16f);
    hipLaunchKernelGGL(ln_qk_kernel, dim3((BATCH * SEQ) / 32), dim3(256), 0, stream,
                       x, ln_w, ln_b, w16f, b_qk, gamma, beta, q_h, k_h);
    hipLaunchKernelGGL(rowsum_kernel, dim3(1024), dim3(512), 0, stream,
                       q_h, k_h, rsum);
    hipLaunchKernelGGL(attn_norm_kernel, dim3(1024), dim3(512), 0, stream,
                       q_h, k_h, rsum, out);
}

// Round 4
// 328.986 us; speedup vs baseline: 1.2474x; 1.0396x over previous
//
#include <hip/hip_runtime.h>

#define DIM 512
#define QKD 128
#define BATCH 4
#define SEQ 4096

typedef __attribute__((ext_vector_type(8)))  _Float16 f16x8;
typedef __attribute__((ext_vector_type(4)))  _Float16 f16x4;
typedef __attribute__((ext_vector_type(4)))  float    f32x4;
typedef __attribute__((ext_vector_type(16))) float    f32x16;

// ---------------------------------------------------------------------------
// Prep: w_qk fp32 -> fp16, permuted to MFMA-fragment order for kernel A:
//   w16f[kc][nb][lane][j] = w[e = nb*16 + (lane&15)][d = kc*32 + (lane>>4)*8 + j]
// ---------------------------------------------------------------------------
__global__ __launch_bounds__(256) void wcvt_kernel(
    const float* __restrict__ w, _Float16* __restrict__ w16f)
{
    const int t    = blockIdx.x * 256 + threadIdx.x;   // 0..8191
    const int lane = t & 63;
    const int nb   = (t >> 6) & 7;
    const int kc   = t >> 9;                           // 0..15
    const int e    = nb * 16 + (lane & 15);
    const int d0   = kc * 32 + (lane >> 4) * 8;
    const float4* src = (const float4*)(w + (size_t)e * DIM + d0);
    const float4 a = src[0], b = src[1];
    f16x8 o;
    o[0] = (_Float16)a.x; o[1] = (_Float16)a.y;
    o[2] = (_Float16)a.z; o[3] = (_Float16)a.w;
    o[4] = (_Float16)b.x; o[5] = (_Float16)b.y;
    o[6] = (_Float16)b.z; o[7] = (_Float16)b.w;
    *(f16x8*)(w16f + (size_t)t * 8) = o;
}

// ---------------------------------------------------------------------------
// Kernel A: LayerNorm + Linear(512->128) + SiLU + OffsetScale -> q,k (fp16)
// R4: 16 rows/block, 1024 blocks (4 waves/SIMD, was grid-limited to 2);
// all 4 rows' x-loads hoisted before any reduce chain (latency hiding);
// epilogue routed through LDS so q/k stores are coalesced f16x8 (was 64
// scattered 2-byte stores per lane).
// Outputs in MFMA-fragment order: off = g*4096 + (e>>3)*256 + (row%32)*8 + (e&7)
// Folds 1/sqrt(4096) as 1/8 into both q and k.
// ---------------------------------------------------------------------------
__global__ __launch_bounds__(256, 4) void ln_qk_kernel(
    const float* __restrict__ x,
    const float* __restrict__ ln_w,
    const float* __restrict__ ln_b,
    const _Float16* __restrict__ w16f,
    const float* __restrict__ b_qk,
    const float* __restrict__ gamma,
    const float* __restrict__ beta,
    _Float16* __restrict__ q_h,
    _Float16* __restrict__ k_h)
{
    __shared__ _Float16 As[16][520];    // LN output, 16B-aligned rows
    __shared__ _Float16 Qs[16][136];    // epilogue staging (136: 16B-aligned rows)
    __shared__ _Float16 Ks[16][136];
    const int tid  = threadIdx.x;
    const int wave = tid >> 6;
    const int lane = tid & 63;
    const int row0 = blockIdx.x * 16;

    // per-lane LN params for d = lane*8 .. +7
    float lw[8], lb[8];
    {
        const float4* w4 = (const float4*)ln_w;
        const float4* b4 = (const float4*)ln_b;
        float4 w0 = w4[lane * 2], w1 = w4[lane * 2 + 1];
        float4 b0 = b4[lane * 2], b1 = b4[lane * 2 + 1];
        lw[0]=w0.x; lw[1]=w0.y; lw[2]=w0.z; lw[3]=w0.w;
        lw[4]=w1.x; lw[5]=w1.y; lw[6]=w1.z; lw[7]=w1.w;
        lb[0]=b0.x; lb[1]=b0.y; lb[2]=b0.z; lb[3]=b0.w;
        lb[4]=b1.x; lb[5]=b1.y; lb[6]=b1.z; lb[7]=b1.w;
    }

    // LN: each wave handles 4 rows; hoist ALL loads first (8 in flight/lane)
    float4 xa[4], xb[4];
#pragma unroll
    for (int rr = 0; rr < 4; ++rr) {
        const float4* xr = (const float4*)(x + (size_t)(row0 + wave * 4 + rr) * DIM);
        xa[rr] = xr[lane * 2];
        xb[rr] = xr[lane * 2 + 1];
    }
#pragma unroll
    for (int rr = 0; rr < 4; ++rr) {
        float xv[8] = {xa[rr].x, xa[rr].y, xa[rr].z, xa[rr].w,
                       xb[rr].x, xb[rr].y, xb[rr].z, xb[rr].w};
        float s = 0.f, s2 = 0.f;
#pragma unroll
        for (int j = 0; j < 8; ++j) { s += xv[j]; s2 = fmaf(xv[j], xv[j], s2); }
#pragma unroll
        for (int off = 32; off > 0; off >>= 1) {
            s  += __shfl_xor(s,  off);
            s2 += __shfl_xor(s2, off);
        }
        const float mu   = s * (1.f / DIM);
        const float var  = s2 * (1.f / DIM) - mu * mu;
        const float rstd = rsqrtf(var + 1e-5f);
        f16x8 hh;
#pragma unroll
        for (int j = 0; j < 8; ++j)
            hh[j] = (_Float16)(fmaf((xv[j] - mu) * rstd, lw[j], lb[j]));
        *(f16x8*)&As[wave * 4 + rr][lane * 8] = hh;
    }
    __syncthreads();

    // GEMM: M=16 (one m-tile), N=128 (each wave owns 2 n-blocks of 16)
    const int lcol = lane & 15;
    const int quad = lane >> 4;

    f32x4 acc[2];
    acc[0] = (f32x4){0.f, 0.f, 0.f, 0.f};
    acc[1] = (f32x4){0.f, 0.f, 0.f, 0.f};

    const _Float16* arow = &As[lcol][quad * 8];
#pragma unroll 4
    for (int kc = 0; kc < 16; ++kc) {
        const f16x8 af = *(const f16x8*)(arow + kc * 32);
#pragma unroll
        for (int nt = 0; nt < 2; ++nt) {
            const f16x8 bfr = *(const f16x8*)(
                w16f + (size_t)((kc * 8 + wave * 2 + nt) * 64 + lane) * 8);
            acc[nt] = __builtin_amdgcn_mfma_f32_16x16x32_f16(af, bfr, acc[nt], 0, 0, 0);
        }
    }

    // epilogue: bias + SiLU + offset-scale (x 1/8) -> LDS staging
#pragma unroll
    for (int nt = 0; nt < 2; ++nt) {
        const int e = (wave * 2 + nt) * 16 + lcol;
        const float bq  = b_qk[e];
        const float g0  = gamma[e]       * 0.125f;
        const float g1  = gamma[QKD + e] * 0.125f;
        const float be0 = beta[e]        * 0.125f;
        const float be1 = beta[QKD + e]  * 0.125f;
#pragma unroll
        for (int reg = 0; reg < 4; ++reg) {
            const int m  = quad * 4 + reg;      // local row 0..15
            const float v   = acc[nt][reg] + bq;
            const float sil = v / (1.f + __expf(-v));
            Qs[m][e] = (_Float16)fmaf(sil, g0, be0);
            Ks[m][e] = (_Float16)fmaf(sil, g1, be1);
        }
    }
    __syncthreads();

    // coalesced store: thread t -> (mm = t&15, eh = t>>4); fragment layout has
    // j innermost so [base..base+7] is contiguous; 16-lane groups form 256-B runs
    {
        const int mm = tid & 15, eh = tid >> 4;
        const f16x8 qv = *(const f16x8*)&Qs[mm][eh * 8];
        const f16x8 kv = *(const f16x8*)&Ks[mm][eh * 8];
        const size_t base = ((size_t)(blockIdx.x >> 1)) * 4096
                          + (size_t)eh * 256 + (blockIdx.x & 1) * 128 + mm * 8;
        *(f16x8*)(q_h + base) = qv;
        *(f16x8*)(k_h + base) = kv;
    }
}

// ---------------------------------------------------------------------------
// Kernel B (fused): per block 32 rows x ALL 4096 cols; pass 1 accumulates
// rowsums of relu(sim)^2 (reduced entirely in LDS), pass 2 recomputes
// (identical MFMA order -> self-consistent) and stores normalized output.
// 512 blocks x 512 thr, VGPR<=128 -> 2 blocks/CU: ALL blocks co-resident,
// zero tail rounds. XCD swizzle pins one batch (1 MB k + 1 MB q) per XCD L2.
// ---------------------------------------------------------------------------
__global__ __launch_bounds__(512, 4) void attn_kernel(
    const _Float16* __restrict__ q_h,
    const _Float16* __restrict__ k_h,
    float* __restrict__ out)
{
    const int l     = blockIdx.x;                    // 0..511
    const int batch = (l & 7) >> 1;
    const int tile  = ((l >> 3) << 1) | (l & 1);     // 0..127

    const int wid  = threadIdx.x >> 6;               // 0..7 col-wave
    const int lane = threadIdx.x & 63;
    const int n    = lane & 31;
    const int h    = lane >> 5;

    // q fragments: contiguous 4 KB block for this 32-row tile
    const _Float16* qb = q_h + (size_t)(batch * 128 + tile) * 4096;
    f16x8 aq[8];
#pragma unroll
    for (int kc = 0; kc < 8; ++kc)
        aq[kc] = *(const f16x8*)(qb + kc * 512 + lane * 8);

    // k col-block g = ct*8 + wid  (col = ct*256 + wid*32 + n)
    const _Float16* kb0 = k_h + (size_t)(batch * 128 + wid) * 4096 + lane * 8;

    __shared__ float partial[8][32];
    __shared__ float srow_s[32];

    float rs[16];
#pragma unroll
    for (int r = 0; r < 16; ++r) rs[r] = 0.f;

    // ---- pass 1: row sums of relu(sim)^2 ----
#pragma unroll 2
    for (int ct = 0; ct < 16; ++ct) {
        const _Float16* cb = kb0 + (size_t)(ct * 8) * 4096;
        f16x8 bf[8];
#pragma unroll
        for (int kc = 0; kc < 8; ++kc) bf[kc] = *(const f16x8*)(cb + kc * 512);

        f32x16 acc;
#pragma unroll
        for (int r = 0; r < 16; ++r) acc[r] = 0.f;
        __builtin_amdgcn_s_setprio(1);
#pragma unroll
        for (int kc = 0; kc < 8; ++kc)
            acc = __builtin_amdgcn_mfma_f32_32x32x16_f16(aq[kc], bf[kc], acc, 0, 0, 0);
        __builtin_amdgcn_s_setprio(0);
#pragma unroll
        for (int r = 0; r < 16; ++r) {
            const float t = fmaxf(acc[r], 0.f);
            rs[r] = fmaf(t, t, rs[r]);
        }
    }

    // reduce across the 32 n-lanes, then across the 8 col-waves (in LDS)
#pragma unroll
    for (int r = 0; r < 16; ++r) {
        float v = rs[r];
        v += __shfl_xor(v, 1);
        v += __shfl_xor(v, 2);
        v += __shfl_xor(v, 4);
        v += __shfl_xor(v, 8);
        v += __shfl_xor(v, 16);
        if (n == 0) partial[wid][(r & 3) + 8 * (r >> 2) + 4 * h] = v;
    }
    __syncthreads();
    if (threadIdx.x < 32) {
        float t = 0.f;
#pragma unroll
        for (int w = 0; w < 8; ++w) t += partial[w][threadIdx.x];
        srow_s[threadIdx.x] = rsqrtf(t + 1e-6f);  // out = (v*srow)^2 = v^2/(sum+1e-6)
    }
    __syncthreads();

    float srow[16];
#pragma unroll
    for (int r = 0; r < 16; ++r)
        srow[r] = srow_s[(r & 3) + 8 * (r >> 2) + 4 * h];

    // ---- pass 2: recompute (identical order) + normalize + nontemporal store ----
    float* ob = out + ((size_t)batch * SEQ + tile * 32) * SEQ;

#pragma unroll 2
    for (int ct = 0; ct < 16; ++ct) {
        const _Float16* cb = kb0 + (size_t)(ct * 8) * 4096;
        f16x8 bf[8];
#pragma unroll
        for (int kc = 0; kc < 8; ++kc) bf[kc] = *(const f16x8*)(cb + kc * 512);

        f32x16 acc;
#pragma unroll
        for (int r = 0; r < 16; ++r) acc[r] = 0.f;
        __builtin_amdgcn_s_setprio(1);
#pragma unroll
        for (int kc = 0; kc < 8; ++kc)
            acc = __builtin_amdgcn_mfma_f32_32x32x16_f16(aq[kc], bf[kc], acc, 0, 0, 0);
        __builtin_amdgcn_s_setprio(0);

        const int col = ct * 256 + wid * 32 + n;
#pragma unroll
        for (int r = 0; r < 16; ++r) {
            const float t   = fmaxf(acc[r], 0.f) * srow[r];
            const int   row = (r & 3) + 8 * (r >> 2) + 4 * h;
            __builtin_nontemporal_store(t * t, ob + (size_t)row * SEQ + col);
        }
    }
}

extern "C" void kernel_launch(void* const* d_in, const int* in_sizes, int n_in,
                              void* d_out, int out_size, void* d_ws, size_t ws_size,
                              hipStream_t stream) {
    const float* x     = (const float*)d_in[0];
    const float* ln_w  = (const float*)d_in[1];
    const float* ln_b  = (const float*)d_in[2];
    const float* w_qk  = (const float*)d_in[3];
    const float* b_qk  = (const float*)d_in[4];
    const float* gamma = (const float*)d_in[5];
    const float* beta  = (const float*)d_in[6];
    float* out = (float*)d_out;

    _Float16* q_h  = (_Float16*)d_ws;                           // 4 MB
    _Float16* k_h  = q_h + (size_t)BATCH * SEQ * QKD;           // 4 MB
    _Float16* w16f = k_h + (size_t)BATCH * SEQ * QKD;           // 128 KB

    hipLaunchKernelGGL(wcvt_kernel, dim3(32), dim3(256), 0, stream, w_qk, w16f);
    hipLaunchKernelGGL(ln_qk_kernel, dim3((BATCH * SEQ) / 16), dim3(256), 0, stream,
                       x, ln_w, ln_b, w16f, b_qk, gamma, beta, q_h, k_h);
    hipLaunchKernelGGL(attn_kernel, dim3(BATCH * (SEQ / 32)), dim3(512), 0, stream,
                       q_h, k_h, out);
}